// Round 9
// baseline (499.128 us; speedup 1.0000x reference)
//
#include <hip/hip_runtime.h>

// ============ R8: INSTRUMENTATION BUILD ============
// aggb_k REP=4, gemm12_k REP=8 (idempotent inner repetition) to lift each
// kernel above the 44 us harness-fill floor so rocprof top-5 shows per-kernel
// dur + counters. Bitwise-OR combine of bit-identical per-rep results keeps
// output exact and defeats DCE; asm memory clobber defeats load-CSE.
// REVERT REP->1 next round.

#define NNODES 10000
#define MP 10112            // 316 * 32 GEMM M-tiles
#define F 256
#define H 512
#define CAP 128             // bucket capacity; Poisson(32) tail @128 ~ 1e-40
#define H1STR 520           // LDS h1 row stride (f16)

typedef _Float16 half8 __attribute__((ext_vector_type(8)));
typedef float floatx4 __attribute__((ext_vector_type(4)));
typedef float floatx8 __attribute__((ext_vector_type(8)));

// ---------- prep: zero cnt + W1^T + W2^T + x->f16 (1250 blocks) ----------
__global__ __launch_bounds__(256) void prep_k(const float* __restrict__ W1,
                                              const float* __restrict__ W2,
                                              const float* __restrict__ x,
                                              _Float16* __restrict__ W1t,
                                              _Float16* __restrict__ W2t,
                                              _Float16* __restrict__ xh,
                                              int* __restrict__ cnt) {
  int gt = blockIdx.x * 256 + threadIdx.x;
  if (gt < NNODES) cnt[gt] = 0;
  if (gt < H * F) {
    W1t[gt] = (_Float16)W1[(gt & 255) * H + (gt >> 8)];
    W2t[gt] = (_Float16)W2[(gt & 511) * F + (gt >> 9)];
  }
  if (gt < NNODES * F / 8) {
    floatx8 v = *(const floatx8*)(x + (size_t)gt * 8);
    *(half8*)(xh + (size_t)gt * 8) = __builtin_convertvector(v, half8);
  }
}

// ---------- bucket CSR build: one pass, cnt ends as degree ----------
__global__ __launch_bounds__(256) void build_k(const int* __restrict__ src,
                                               const int* __restrict__ dst,
                                               int* __restrict__ cnt,
                                               int* __restrict__ csr, int E) {
  int e = blockIdx.x * blockDim.x + threadIdx.x;
  if (e < E) {
    int d = dst[e];
    int p = atomicAdd(&cnt[d], 1);
    if (p < CAP) csr[(size_t)d * CAP + p] = src[e];
  }
}

// ---------- half-wave-per-node aggregation over f16 rows (F=256) ----------
template <bool FUSE_MAX, int REP>
__global__ __launch_bounds__(256) void aggb_k(const _Float16* __restrict__ in,
                                              const int* __restrict__ cnt,
                                              const int* __restrict__ csr,
                                              const float* __restrict__ bias,
                                              _Float16* __restrict__ outh,
                                              float* __restrict__ out) {
  __shared__ float smem[2048];
  int tid = threadIdx.x;
  int lane = tid & 63, wvi = tid >> 6;
  int half = lane >> 5, hl = lane & 31;
  int f0 = hl * 8;
  int node = (blockIdx.x * 4 + wvi) * 2 + half;   // grid 1250 -> node < 10000
  floatx8 bb = {};
  if (FUSE_MAX) bb = *(const floatx8*)(bias + f0);
  int deg = min(cnt[node], CAP);
  float di = rsqrtf((float)(deg + 1));
  const int* bucket = csr + (size_t)node * CAP;
  int totb[8] = {0, 0, 0, 0, 0, 0, 0, 0};
  #pragma unroll 1
  for (int rep = 0; rep < REP; rep++) {
    asm volatile("" ::: "memory");   // force re-load each rep (no CSE)
    floatx8 acc = {};
    for (int c = 0; c < deg; c += 32) {
      int mm = min(32, deg - c);
      int sv = 0; float wvv = 0.f;
      if (hl < mm) {
        sv = bucket[c + hl];
        wvv = rsqrtf((float)(cnt[sv] + 1));
      }
      #pragma unroll
      for (int b = 0; b < 2; b++) {
        int base = b * 16;
        if (base < mm) {
          int sj[16]; float wj[16];
          #pragma unroll
          for (int u = 0; u < 16; u++) {
            int l = (half << 5) | (base + u);
            sj[u] = __shfl(sv, l, 64);
            wj[u] = __shfl(wvv, l, 64);
          }
          half8 hv[16];
          #pragma unroll
          for (int u = 0; u < 16; u++)
            hv[u] = *(const half8*)(in + (size_t)sj[u] * F + f0);
          #pragma unroll
          for (int u = 0; u < 16; u++)
            acc += wj[u] * __builtin_convertvector(hv[u], floatx8);
        }
      }
    }
    half8 xsv = *(const half8*)(in + (size_t)node * F + f0);
    floatx8 t8 = di * acc + (di * di) * __builtin_convertvector(xsv, floatx8);
    // per-rep values are bit-identical; OR is exact identity but keeps
    // every rep live (no DCE)
    #pragma unroll
    for (int t = 0; t < 8; t++) totb[t] |= __float_as_int(t8[t]);
  }
  floatx8 tot;
  #pragma unroll
  for (int t = 0; t < 8; t++) tot[t] = __int_as_float(totb[t]);
  if (FUSE_MAX) {
    tot += bb;
    floatx8 lmax;
    #pragma unroll
    for (int t = 0; t < 8; t++) lmax[t] = fmaxf(tot[t], 0.f);
    float* srow = smem + (size_t)(wvi * 2 + half) * 256;
    *(floatx8*)(srow + f0) = lmax;
    __syncthreads();
    float m = smem[tid];
    #pragma unroll
    for (int r = 1; r < 8; r++) m = fmaxf(m, smem[r * 256 + tid]);
    // relu outputs >= 0; out poison/zero is <= 0 as int -> atomicMax correct
    atomicMax((int*)&out[tid], __float_as_int(m));
  } else {
    *(half8*)(outh + (size_t)node * F + f0) = __builtin_convertvector(tot, half8);
  }
}

// ---------- fused GEMM1+GEMM2 per 32-row tile ----------
template <int REP>
__global__ __launch_bounds__(256) void gemm12_k(const _Float16* __restrict__ A,
                                                const _Float16* __restrict__ W1t,
                                                const float* __restrict__ b1,
                                                const _Float16* __restrict__ W2t,
                                                _Float16* __restrict__ C) {
  __shared__ _Float16 h1[32 * H1STR];   // 32*520*2 = 33,280 B
  int lane = threadIdx.x & 63;
  int wv = threadIdx.x >> 6;
  int r = lane & 15, q = lane >> 4;
  int m0 = blockIdx.x * 32;

  #pragma unroll 1
  for (int rep = 0; rep < REP; rep++) {
    asm volatile("" ::: "memory");   // force re-load each rep
    // ---- phase 1: gemm1, wave wv covers cols [wv*128, wv*128+128) ----
    {
      floatx4 acc[2][8] = {};
      const _Float16* Ap = A + (size_t)(m0 + r) * F + q * 8;
      const _Float16* Bp = W1t + (size_t)(wv * 128 + r) * F + q * 8;
      for (int k0 = 0; k0 < F; k0 += 32) {
        half8 a[2], b[8];
        #pragma unroll
        for (int i = 0; i < 2; i++) a[i] = *(const half8*)(Ap + (size_t)i * 16 * F + k0);
        #pragma unroll
        for (int j = 0; j < 8; j++) b[j] = *(const half8*)(Bp + (size_t)j * 16 * F + k0);
        #pragma unroll
        for (int i = 0; i < 2; i++)
          #pragma unroll
          for (int j = 0; j < 8; j++)
            acc[i][j] = __builtin_amdgcn_mfma_f32_16x16x32_f16(a[i], b[j], acc[i][j], 0, 0, 0);
      }
      #pragma unroll
      for (int i = 0; i < 2; i++) {
        #pragma unroll
        for (int j = 0; j < 8; j++) {
          int n = wv * 128 + j * 16 + r;
          float bv = b1[n];
          #pragma unroll
          for (int rr = 0; rr < 4; rr++) {
            int row = i * 16 + q * 4 + rr;
            h1[row * H1STR + n] = (_Float16)fmaxf(acc[i][j][rr] + bv, 0.f);
          }
        }
      }
    }
    __syncthreads();

    // ---- phase 2: gemm2 from LDS h1, wave wv covers cols [wv*64, wv*64+64) ----
    {
      floatx4 acc[2][4] = {};
      const _Float16* Bp = W2t + (size_t)(wv * 64 + r) * H + q * 8;
      for (int k0 = 0; k0 < H; k0 += 32) {
        half8 a[2], b[4];
        #pragma unroll
        for (int i = 0; i < 2; i++)
          a[i] = *(const half8*)(h1 + (i * 16 + r) * H1STR + k0 + q * 8);
        #pragma unroll
        for (int j = 0; j < 4; j++) b[j] = *(const half8*)(Bp + (size_t)j * 16 * H + k0);
        #pragma unroll
        for (int i = 0; i < 2; i++)
          #pragma unroll
          for (int j = 0; j < 4; j++)
            acc[i][j] = __builtin_amdgcn_mfma_f32_16x16x32_f16(a[i], b[j], acc[i][j], 0, 0, 0);
      }
      #pragma unroll
      for (int i = 0; i < 2; i++) {
        #pragma unroll
        for (int j = 0; j < 4; j++) {
          int n = wv * 64 + j * 16 + r;
          #pragma unroll
          for (int rr = 0; rr < 4; rr++) {
            int row = m0 + i * 16 + q * 4 + rr;
            C[(size_t)row * F + n] = (_Float16)acc[i][j][rr];   // same value each rep
          }
        }
      }
    }
    __syncthreads();   // h1 not overwritten until all waves finish phase 2
  }
}

extern "C" void kernel_launch(void* const* d_in, const int* in_sizes, int n_in,
                              void* d_out, int out_size, void* d_ws, size_t ws_size,
                              hipStream_t stream) {
  const float* x  = (const float*)d_in[0];
  const int*   ei = (const int*)d_in[1];
  const float* W1 = (const float*)d_in[2];
  const float* b1 = (const float*)d_in[3];
  const float* W2 = (const float*)d_in[4];
  const float* b2 = (const float*)d_in[5];
  const int E = in_sizes[1] / 2;
  const int N = NNODES;
  const int* src = ei;
  const int* dst = ei + E;

  char* w = (char*)d_ws;
  size_t off = 0;
  auto take = [&](size_t bytes) -> void* {
    void* p = w + off;
    off += (bytes + 255) & ~(size_t)255;
    return p;
  };
  int*       cnt    = (int*)take((size_t)N * 4);
  int*       csr    = (int*)take((size_t)N * CAP * 4);
  _Float16*  W1t    = (_Float16*)take((size_t)H * F * 2);
  _Float16*  W2t    = (_Float16*)take((size_t)F * H * 2);
  _Float16*  xh     = (_Float16*)take((size_t)N * F * 2);
  _Float16*  axh    = (_Float16*)take((size_t)MP * F * 2);   // padded M
  _Float16*  xw2h   = (_Float16*)take((size_t)MP * F * 2);   // padded M

  prep_k<<<1250, 256, 0, stream>>>(W1, W2, x, W1t, W2t, xh, cnt);
  build_k<<<(E + 255) / 256, 256, 0, stream>>>(src, dst, cnt, csr, E);
  aggb_k<false, 4><<<1250, 256, 0, stream>>>(xh, cnt, csr, nullptr, axh, nullptr);
  gemm12_k<8><<<MP / 32, 256, 0, stream>>>(axh, W1t, b1, W2t, xw2h);
  aggb_k<true, 4><<<1250, 256, 0, stream>>>(xw2h, cnt, csr, b2, nullptr, (float*)d_out);
}

// Round 10
// 192.458 us; speedup vs baseline: 2.5934x; 2.5934x over previous
//
#include <hip/hip_runtime.h>

#define NNODES 10000
#define MP 10112            // 632 * 16 GEMM M-tiles
#define F 256
#define H 512
#define CAP 128             // bucket capacity; Poisson(32) tail @128 ~ 1e-40
#define H1STR 520           // LDS h1 row stride (f16)

typedef _Float16 half8 __attribute__((ext_vector_type(8)));
typedef float floatx4 __attribute__((ext_vector_type(4)));
typedef float floatx8 __attribute__((ext_vector_type(8)));

// ---------- prep: zero cnt + W1^T + W2^T + x->f16 (1250 blocks) ----------
__global__ __launch_bounds__(256) void prep_k(const float* __restrict__ W1,
                                              const float* __restrict__ W2,
                                              const float* __restrict__ x,
                                              _Float16* __restrict__ W1t,
                                              _Float16* __restrict__ W2t,
                                              _Float16* __restrict__ xh,
                                              int* __restrict__ cnt) {
  int gt = blockIdx.x * 256 + threadIdx.x;
  if (gt < NNODES) cnt[gt] = 0;
  if (gt < H * F) {
    W1t[gt] = (_Float16)W1[(gt & 255) * H + (gt >> 8)];
    W2t[gt] = (_Float16)W2[(gt & 511) * F + (gt >> 9)];
  }
  if (gt < NNODES * F / 8) {
    floatx8 v = *(const floatx8*)(x + (size_t)gt * 8);
    *(half8*)(xh + (size_t)gt * 8) = __builtin_convertvector(v, half8);
  }
}

// ---------- bucket CSR build: one pass, cnt ends as degree ----------
__global__ __launch_bounds__(256) void build_k(const int* __restrict__ src,
                                               const int* __restrict__ dst,
                                               int* __restrict__ cnt,
                                               int* __restrict__ csr, int E) {
  int e = blockIdx.x * blockDim.x + threadIdx.x;
  if (e < E) {
    int d = dst[e];
    int p = atomicAdd(&cnt[d], 1);
    if (p < CAP) csr[(size_t)d * CAP + p] = src[e];
  }
}

// ---------- half-wave-per-node aggregation over f16 rows (F=256) ----------
template <bool FUSE_MAX>
__global__ __launch_bounds__(256) void aggb_k(const _Float16* __restrict__ in,
                                              const int* __restrict__ cnt,
                                              const int* __restrict__ csr,
                                              const float* __restrict__ bias,
                                              _Float16* __restrict__ outh,
                                              float* __restrict__ out) {
  __shared__ float smem[2048];
  int tid = threadIdx.x;
  int lane = tid & 63, wvi = tid >> 6;
  int half = lane >> 5, hl = lane & 31;
  int f0 = hl * 8;
  int node = (blockIdx.x * 4 + wvi) * 2 + half;   // grid 1250 -> node < 10000
  floatx8 bb = {};
  if (FUSE_MAX) bb = *(const floatx8*)(bias + f0);
  int deg = min(cnt[node], CAP);
  float di = rsqrtf((float)(deg + 1));
  const int* bucket = csr + (size_t)node * CAP;
  floatx8 acc = {};
  for (int c = 0; c < deg; c += 32) {
    int mm = min(32, deg - c);
    int sv = 0; float wvv = 0.f;
    if (hl < mm) {
      sv = bucket[c + hl];
      wvv = rsqrtf((float)(cnt[sv] + 1));
    }
    #pragma unroll
    for (int b = 0; b < 2; b++) {
      int base = b * 16;
      if (base < mm) {
        int sj[16]; float wj[16];
        #pragma unroll
        for (int u = 0; u < 16; u++) {
          int l = (half << 5) | (base + u);
          sj[u] = __shfl(sv, l, 64);
          wj[u] = __shfl(wvv, l, 64);
        }
        half8 hv[16];
        #pragma unroll
        for (int u = 0; u < 16; u++)
          hv[u] = *(const half8*)(in + (size_t)sj[u] * F + f0);
        #pragma unroll
        for (int u = 0; u < 16; u++)
          acc += wj[u] * __builtin_convertvector(hv[u], floatx8);
      }
    }
  }
  half8 xsv = *(const half8*)(in + (size_t)node * F + f0);
  floatx8 tot = di * acc + (di * di) * __builtin_convertvector(xsv, floatx8);
  if (FUSE_MAX) {
    tot += bb;
    floatx8 lmax;
    #pragma unroll
    for (int t = 0; t < 8; t++) lmax[t] = fmaxf(tot[t], 0.f);
    float* srow = smem + (size_t)(wvi * 2 + half) * 256;
    *(floatx8*)(srow + f0) = lmax;
    __syncthreads();
    float m = smem[tid];
    #pragma unroll
    for (int r = 1; r < 8; r++) m = fmaxf(m, smem[r * 256 + tid]);
    // relu outputs >= 0; out poison/zero is <= 0 as int -> atomicMax correct
    atomicMax((int*)&out[tid], __float_as_int(m));
  } else {
    *(half8*)(outh + (size_t)node * F + f0) = __builtin_convertvector(tot, half8);
  }
}

// ---------- fused GEMM1+GEMM2, 16-row tiles (632 blocks) ----------
// R9 redesign: was 32-row/316 blocks, VGPR 196 -> 1.2 blocks/CU, 1 wave/SIMD,
// unhidden latency chain (40 us, Occ 7.4%, MfmaUtil 5.3%). Now 16-row tiles:
// 632 blocks (2.5/CU), acc 32 VGPR/wave phase-1 -> target ~10 waves/CU so
// cross-wave overlap hides L2 latency.
// h1(16x512) = relu(A(16x256) @ W1t^T + b1) in LDS; C(16x256) = h1 @ W2t^T.
__global__ __launch_bounds__(256) void gemm12_k(const _Float16* __restrict__ A,
                                                const _Float16* __restrict__ W1t,
                                                const float* __restrict__ b1,
                                                const _Float16* __restrict__ W2t,
                                                _Float16* __restrict__ C) {
  __shared__ _Float16 h1[16 * H1STR];   // 16,640 B
  int lane = threadIdx.x & 63;
  int wv = threadIdx.x >> 6;
  int r = lane & 15, q = lane >> 4;
  int m0 = blockIdx.x * 16;

  // ---- phase 1: wave wv covers h1 cols [wv*128, wv*128+128) ----
  {
    floatx4 acc[8] = {};
    const _Float16* Ap = A + (size_t)(m0 + r) * F + q * 8;
    const _Float16* Bp = W1t + (size_t)(wv * 128 + r) * F + q * 8;
    for (int k0 = 0; k0 < F; k0 += 32) {
      half8 a = *(const half8*)(Ap + k0);
      half8 b[8];
      #pragma unroll
      for (int j = 0; j < 8; j++) b[j] = *(const half8*)(Bp + (size_t)j * 16 * F + k0);
      #pragma unroll
      for (int j = 0; j < 8; j++)
        acc[j] = __builtin_amdgcn_mfma_f32_16x16x32_f16(a, b[j], acc[j], 0, 0, 0);
    }
    #pragma unroll
    for (int j = 0; j < 8; j++) {
      int n = wv * 128 + j * 16 + r;
      float bv = b1[n];
      #pragma unroll
      for (int rr = 0; rr < 4; rr++)
        h1[(q * 4 + rr) * H1STR + n] = (_Float16)fmaxf(acc[j][rr] + bv, 0.f);
    }
  }
  __syncthreads();

  // ---- phase 2: wave wv covers C cols [wv*64, wv*64+64) ----
  {
    floatx4 acc[4] = {};
    const _Float16* Bp = W2t + (size_t)(wv * 64 + r) * H + q * 8;
    for (int k0 = 0; k0 < H; k0 += 32) {
      half8 a = *(const half8*)(h1 + r * H1STR + k0 + q * 8);
      half8 b[4];
      #pragma unroll
      for (int j = 0; j < 4; j++) b[j] = *(const half8*)(Bp + (size_t)j * 16 * H + k0);
      #pragma unroll
      for (int j = 0; j < 4; j++)
        acc[j] = __builtin_amdgcn_mfma_f32_16x16x32_f16(a, b[j], acc[j], 0, 0, 0);
    }
    #pragma unroll
    for (int j = 0; j < 4; j++) {
      int n = wv * 64 + j * 16 + r;
      #pragma unroll
      for (int rr = 0; rr < 4; rr++) {
        int row = m0 + q * 4 + rr;
        C[(size_t)row * F + n] = (_Float16)acc[j][rr];
      }
    }
  }
}

extern "C" void kernel_launch(void* const* d_in, const int* in_sizes, int n_in,
                              void* d_out, int out_size, void* d_ws, size_t ws_size,
                              hipStream_t stream) {
  const float* x  = (const float*)d_in[0];
  const int*   ei = (const int*)d_in[1];
  const float* W1 = (const float*)d_in[2];
  const float* b1 = (const float*)d_in[3];
  const float* W2 = (const float*)d_in[4];
  const float* b2 = (const float*)d_in[5];
  const int E = in_sizes[1] / 2;
  const int N = NNODES;
  const int* src = ei;
  const int* dst = ei + E;

  char* w = (char*)d_ws;
  size_t off = 0;
  auto take = [&](size_t bytes) -> void* {
    void* p = w + off;
    off += (bytes + 255) & ~(size_t)255;
    return p;
  };
  int*       cnt    = (int*)take((size_t)N * 4);
  int*       csr    = (int*)take((size_t)N * CAP * 4);
  _Float16*  W1t    = (_Float16*)take((size_t)H * F * 2);
  _Float16*  W2t    = (_Float16*)take((size_t)F * H * 2);
  _Float16*  xh     = (_Float16*)take((size_t)N * F * 2);
  _Float16*  axh    = (_Float16*)take((size_t)MP * F * 2);   // padded M
  _Float16*  xw2h   = (_Float16*)take((size_t)MP * F * 2);   // padded M

  prep_k<<<1250, 256, 0, stream>>>(W1, W2, x, W1t, W2t, xh, cnt);
  build_k<<<(E + 255) / 256, 256, 0, stream>>>(src, dst, cnt, csr, E);
  aggb_k<false><<<1250, 256, 0, stream>>>(xh, cnt, csr, nullptr, axh, nullptr);
  gemm12_k<<<MP / 16, 256, 0, stream>>>(axh, W1t, b1, W2t, xw2h);
  aggb_k<true><<<1250, 256, 0, stream>>>(xw2h, cnt, csr, b2, nullptr, (float*)d_out);
}

// Round 11
// 189.882 us; speedup vs baseline: 2.6286x; 1.0136x over previous
//
#include <hip/hip_runtime.h>

#define NNODES 10000
#define MP 10112            // 632 * 16 GEMM M-tiles
#define F 256
#define H 512
#define CAP 128             // bucket capacity; Poisson(32) tail @128 ~ 1e-40
#define H1STR 520           // LDS h1 row stride (f16)

typedef _Float16 half8 __attribute__((ext_vector_type(8)));
typedef float floatx4 __attribute__((ext_vector_type(4)));
typedef float floatx8 __attribute__((ext_vector_type(8)));

// ---------- prep: zero cnt + W1^T + W2^T + x->f16 (1250 blocks) ----------
__global__ __launch_bounds__(256) void prep_k(const float* __restrict__ W1,
                                              const float* __restrict__ W2,
                                              const float* __restrict__ x,
                                              _Float16* __restrict__ W1t,
                                              _Float16* __restrict__ W2t,
                                              _Float16* __restrict__ xh,
                                              int* __restrict__ cnt) {
  int gt = blockIdx.x * 256 + threadIdx.x;
  if (gt < NNODES) cnt[gt] = 0;
  if (gt < H * F) {
    W1t[gt] = (_Float16)W1[(gt & 255) * H + (gt >> 8)];
    W2t[gt] = (_Float16)W2[(gt & 511) * F + (gt >> 9)];
  }
  if (gt < NNODES * F / 8) {
    floatx8 v = *(const floatx8*)(x + (size_t)gt * 8);
    *(half8*)(xh + (size_t)gt * 8) = __builtin_convertvector(v, half8);
  }
}

// ---------- bucket CSR build: one pass, cnt ends as degree ----------
__global__ __launch_bounds__(256) void build_k(const int* __restrict__ src,
                                               const int* __restrict__ dst,
                                               int* __restrict__ cnt,
                                               int* __restrict__ csr, int E) {
  int e = blockIdx.x * blockDim.x + threadIdx.x;
  if (e < E) {
    int d = dst[e];
    int p = atomicAdd(&cnt[d], 1);
    if (p < CAP) csr[(size_t)d * CAP + p] = src[e];
  }
}

// ---------- half-wave-per-node aggregation over f16 rows (F=256) ----------
template <bool FUSE_MAX>
__global__ __launch_bounds__(256) void aggb_k(const _Float16* __restrict__ in,
                                              const int* __restrict__ cnt,
                                              const int* __restrict__ csr,
                                              const float* __restrict__ bias,
                                              _Float16* __restrict__ outh,
                                              float* __restrict__ out) {
  __shared__ float smem[2048];
  int tid = threadIdx.x;
  int lane = tid & 63, wvi = tid >> 6;
  int half = lane >> 5, hl = lane & 31;
  int f0 = hl * 8;
  int node = (blockIdx.x * 4 + wvi) * 2 + half;   // grid 1250 -> node < 10000
  floatx8 bb = {};
  if (FUSE_MAX) bb = *(const floatx8*)(bias + f0);
  int deg = min(cnt[node], CAP);
  float di = rsqrtf((float)(deg + 1));
  const int* bucket = csr + (size_t)node * CAP;
  floatx8 acc = {};
  for (int c = 0; c < deg; c += 32) {
    int mm = min(32, deg - c);
    int sv = 0; float wvv = 0.f;
    if (hl < mm) {
      sv = bucket[c + hl];
      wvv = rsqrtf((float)(cnt[sv] + 1));
    }
    #pragma unroll
    for (int b = 0; b < 2; b++) {
      int base = b * 16;
      if (base < mm) {
        int sj[16]; float wj[16];
        #pragma unroll
        for (int u = 0; u < 16; u++) {
          int l = (half << 5) | (base + u);
          sj[u] = __shfl(sv, l, 64);
          wj[u] = __shfl(wvv, l, 64);
        }
        half8 hv[16];
        #pragma unroll
        for (int u = 0; u < 16; u++)
          hv[u] = *(const half8*)(in + (size_t)sj[u] * F + f0);
        #pragma unroll
        for (int u = 0; u < 16; u++)
          acc += wj[u] * __builtin_convertvector(hv[u], floatx8);
      }
    }
  }
  half8 xsv = *(const half8*)(in + (size_t)node * F + f0);
  floatx8 tot = di * acc + (di * di) * __builtin_convertvector(xsv, floatx8);
  if (FUSE_MAX) {
    tot += bb;
    floatx8 lmax;
    #pragma unroll
    for (int t = 0; t < 8; t++) lmax[t] = fmaxf(tot[t], 0.f);
    float* srow = smem + (size_t)(wvi * 2 + half) * 256;
    *(floatx8*)(srow + f0) = lmax;
    __syncthreads();
    float m = smem[tid];
    #pragma unroll
    for (int r = 1; r < 8; r++) m = fmaxf(m, smem[r * 256 + tid]);
    // relu outputs >= 0; out poison/zero is <= 0 as int -> atomicMax correct
    atomicMax((int*)&out[tid], __float_as_int(m));
  } else {
    *(half8*)(outh + (size_t)node * F + f0) = __builtin_convertvector(tot, half8);
  }
}

// ---------- fused GEMM1+GEMM2, 16-row tiles, register-prefetched ----------
// R10 fix: R9's bare launch_bounds(256) let the allocator target 8 waves/SIMD
// (VGPR=60 < the 68 live regs phase 1 needs) -> per-fragment load->waitcnt->
// MFMA serialization, ~300 cyc/load, 50 us. Now __launch_bounds__(256,2)
// (VGPR cap 256) + explicit next-k prefetch: ~18 loads in flight per wave,
// 2 blocks/CU co-resident -> latency hidden; floor = L2 weight stream ~9 us.
__global__ __launch_bounds__(256, 2) void gemm12_k(const _Float16* __restrict__ A,
                                                   const _Float16* __restrict__ W1t,
                                                   const float* __restrict__ b1,
                                                   const _Float16* __restrict__ W2t,
                                                   _Float16* __restrict__ C) {
  __shared__ _Float16 h1[16 * H1STR];   // 16,640 B
  int lane = threadIdx.x & 63;
  int wv = threadIdx.x >> 6;
  int r = lane & 15, q = lane >> 4;
  int m0 = blockIdx.x * 16;

  // ---- phase 1: wave wv covers h1 cols [wv*128, wv*128+128) ----
  {
    floatx4 acc[8] = {};
    const _Float16* Ap = A + (size_t)(m0 + r) * F + q * 8;
    const _Float16* Bp = W1t + (size_t)(wv * 128 + r) * F + q * 8;
    half8 a = *(const half8*)(Ap);
    half8 b[8];
    #pragma unroll
    for (int j = 0; j < 8; j++) b[j] = *(const half8*)(Bp + (size_t)j * 16 * F);
    for (int k0 = 0; k0 < F; k0 += 32) {
      half8 an{}, bn[8];
      if (k0 + 32 < F) {                       // prefetch next k-step
        an = *(const half8*)(Ap + k0 + 32);
        #pragma unroll
        for (int j = 0; j < 8; j++)
          bn[j] = *(const half8*)(Bp + (size_t)j * 16 * F + k0 + 32);
      }
      #pragma unroll
      for (int j = 0; j < 8; j++)
        acc[j] = __builtin_amdgcn_mfma_f32_16x16x32_f16(a, b[j], acc[j], 0, 0, 0);
      a = an;
      #pragma unroll
      for (int j = 0; j < 8; j++) b[j] = bn[j];
    }
    #pragma unroll
    for (int j = 0; j < 8; j++) {
      int n = wv * 128 + j * 16 + r;
      float bv = b1[n];
      #pragma unroll
      for (int rr = 0; rr < 4; rr++)
        h1[(q * 4 + rr) * H1STR + n] = (_Float16)fmaxf(acc[j][rr] + bv, 0.f);
    }
  }
  __syncthreads();

  // ---- phase 2: wave wv covers C cols [wv*64, wv*64+64) ----
  {
    floatx4 acc[4] = {};
    const _Float16* Bp = W2t + (size_t)(wv * 64 + r) * H + q * 8;
    half8 a = *(const half8*)(h1 + r * H1STR + q * 8);
    half8 b[4];
    #pragma unroll
    for (int j = 0; j < 4; j++) b[j] = *(const half8*)(Bp + (size_t)j * 16 * H);
    for (int k0 = 0; k0 < H; k0 += 32) {
      half8 an{}, bn[4];
      if (k0 + 32 < H) {
        an = *(const half8*)(h1 + r * H1STR + k0 + 32 + q * 8);
        #pragma unroll
        for (int j = 0; j < 4; j++)
          bn[j] = *(const half8*)(Bp + (size_t)j * 16 * H + k0 + 32);
      }
      #pragma unroll
      for (int j = 0; j < 4; j++)
        acc[j] = __builtin_amdgcn_mfma_f32_16x16x32_f16(a, b[j], acc[j], 0, 0, 0);
      a = an;
      #pragma unroll
      for (int j = 0; j < 4; j++) b[j] = bn[j];
    }
    #pragma unroll
    for (int j = 0; j < 4; j++) {
      int n = wv * 64 + j * 16 + r;
      #pragma unroll
      for (int rr = 0; rr < 4; rr++) {
        int row = m0 + q * 4 + rr;
        C[(size_t)row * F + n] = (_Float16)acc[j][rr];
      }
    }
  }
}

extern "C" void kernel_launch(void* const* d_in, const int* in_sizes, int n_in,
                              void* d_out, int out_size, void* d_ws, size_t ws_size,
                              hipStream_t stream) {
  const float* x  = (const float*)d_in[0];
  const int*   ei = (const int*)d_in[1];
  const float* W1 = (const float*)d_in[2];
  const float* b1 = (const float*)d_in[3];
  const float* W2 = (const float*)d_in[4];
  const float* b2 = (const float*)d_in[5];
  const int E = in_sizes[1] / 2;
  const int N = NNODES;
  const int* src = ei;
  const int* dst = ei + E;

  char* w = (char*)d_ws;
  size_t off = 0;
  auto take = [&](size_t bytes) -> void* {
    void* p = w + off;
    off += (bytes + 255) & ~(size_t)255;
    return p;
  };
  int*       cnt    = (int*)take((size_t)N * 4);
  int*       csr    = (int*)take((size_t)N * CAP * 4);
  _Float16*  W1t    = (_Float16*)take((size_t)H * F * 2);
  _Float16*  W2t    = (_Float16*)take((size_t)F * H * 2);
  _Float16*  xh     = (_Float16*)take((size_t)N * F * 2);
  _Float16*  axh    = (_Float16*)take((size_t)MP * F * 2);   // padded M
  _Float16*  xw2h   = (_Float16*)take((size_t)MP * F * 2);   // padded M

  prep_k<<<1250, 256, 0, stream>>>(W1, W2, x, W1t, W2t, xh, cnt);
  build_k<<<(E + 255) / 256, 256, 0, stream>>>(src, dst, cnt, csr, E);
  aggb_k<false><<<1250, 256, 0, stream>>>(xh, cnt, csr, nullptr, axh, nullptr);
  gemm12_k<<<MP / 16, 256, 0, stream>>>(axh, W1t, b1, W2t, xw2h);
  aggb_k<true><<<1250, 256, 0, stream>>>(xw2h, cnt, csr, b2, nullptr, (float*)d_out);
}